// Round 1
// 5544.156 us; speedup vs baseline: 5.2322x; 5.2322x over previous
//
#include <hip/hip_runtime.h>
#include <math.h>

#define T_ 64
#define B_ 32
#define V_ 32000
#define H_ 1024
#define EMB_ 512
#define EPS_ 1e-7f
#define COPY_ID_ 3

typedef __bf16 bf16x8 __attribute__((ext_vector_type(8)));
typedef float f32x4 __attribute__((ext_vector_type(4)));

__device__ __forceinline__ unsigned short f2bf(float x) {
    union { float f; unsigned int i; } v; v.f = x;
    unsigned int r = v.i + 0x7FFF + ((v.i >> 16) & 1);
    return (unsigned short)(r >> 16);
}
__device__ __forceinline__ float bf2f(unsigned short h) {
    union { unsigned int i; float f; } v; v.i = ((unsigned int)h) << 16;
    return v.f;
}
// split v into hi + lo bf16 (RNE); hi+lo reproduces v to ~2^-17 rel.
__device__ __forceinline__ void f2hilo(float v, unsigned short& h, unsigned short& l) {
    h = f2bf(v);
    l = f2bf(v - bf2f(h));
}

// ---------------------------------------------------------------------------
// One-time weight packing: gate-interleaved rows (i,f,g,o adjacent per unit),
// [Wih | Whh] concatenated along K, split into bf16 hi/lo.
// row jp: unit u = jp>>2, gate g = jp&3, original row j = g*H + u.
// ---------------------------------------------------------------------------
__global__ __launch_bounds__(256) void pack_gates_kernel(
    const float* __restrict__ Wih, int Kih, const float* __restrict__ Whh,
    int Kout, unsigned short* __restrict__ hi, unsigned short* __restrict__ lo)
{
    int idx = blockIdx.x * 256 + threadIdx.x;   // float4 index, row-major [4096][Kout/4]
    int kq = Kout >> 2;
    int jp = idx / kq;
    if (jp >= 4096) return;
    int k = (idx - jp * kq) << 2;
    int j = (jp & 3) * H_ + (jp >> 2);
    float4 v = (k < Kih) ? *(const float4*)(Wih + (size_t)j * Kih + k)
                         : *(const float4*)(Whh + (size_t)j * H_ + (k - Kih));
    unsigned short h0,l0,h1,l1,h2,l2,h3,l3;
    f2hilo(v.x,h0,l0); f2hilo(v.y,h1,l1); f2hilo(v.z,h2,l2); f2hilo(v.w,h3,l3);
    ushort4 vh; vh.x=h0; vh.y=h1; vh.z=h2; vh.w=h3;
    ushort4 vl; vl.x=l0; vl.y=l1; vl.z=l2; vl.w=l3;
    ((ushort4*)hi)[idx] = vh;
    ((ushort4*)lo)[idx] = vl;
}

__global__ __launch_bounds__(256) void pack_plain_kernel(
    const float* __restrict__ W, unsigned short* __restrict__ hi,
    unsigned short* __restrict__ lo, int n4)
{
    int idx = blockIdx.x * 256 + threadIdx.x;
    if (idx >= n4) return;
    float4 v = ((const float4*)W)[idx];
    unsigned short h0,l0,h1,l1,h2,l2,h3,l3;
    f2hilo(v.x,h0,l0); f2hilo(v.y,h1,l1); f2hilo(v.z,h2,l2); f2hilo(v.w,h3,l3);
    ushort4 vh; vh.x=h0; vh.y=h1; vh.z=h2; vh.w=h3;
    ushort4 vl; vl.x=l0; vl.y=l1; vl.z=l2; vl.w=l3;
    ((ushort4*)hi)[idx] = vh;
    ((ushort4*)lo)[idx] = vl;
}

// Gather embeddings for all (t,b) up front into bf16 hi/lo: Xe[T*B][512].
__global__ __launch_bounds__(256) void embed_hilo_kernel(
    const float* __restrict__ E, const int* __restrict__ tok,
    unsigned short* __restrict__ Xh, unsigned short* __restrict__ Xl)
{
    int idx = blockIdx.x * 256 + threadIdx.x;   // over 2048*128 float4s
    int row = idx >> 7, k = (idx & 127) << 2;
    int tv = tok[row];
    float4 v = *(const float4*)(E + (size_t)tv * EMB_ + k);
    unsigned short h0,l0,h1,l1,h2,l2,h3,l3;
    f2hilo(v.x,h0,l0); f2hilo(v.y,h1,l1); f2hilo(v.z,h2,l2); f2hilo(v.w,h3,l3);
    ushort4 vh; vh.x=h0; vh.y=h1; vh.z=h2; vh.w=h3;
    ushort4 vl; vl.x=l0; vl.y=l1; vl.z=l2; vl.w=l3;
    ((ushort4*)Xh)[idx] = vh;
    ((ushort4*)Xl)[idx] = vl;
}

// Init ping-pong recurrent input buffers (t=0 parity): feed/h0slot zero,
// hprev slots from h0 initial states.
__global__ __launch_bounds__(256) void init_states_kernel(
    const float* __restrict__ h0i,
    unsigned short* __restrict__ x0h, unsigned short* __restrict__ x0l,
    unsigned short* __restrict__ x1h, unsigned short* __restrict__ x1l)
{
    int idx = blockIdx.x * 256 + threadIdx.x;   // 32*1024
    int b = idx >> 10, u = idx & 1023;
    unsigned short h, l;
    x0h[b*2048 + u] = 0; x0l[b*2048 + u] = 0;
    f2hilo(h0i[idx], h, l);
    x0h[b*2048 + 1024 + u] = h; x0l[b*2048 + 1024 + u] = l;
    x1h[b*2048 + u] = 0; x1l[b*2048 + u] = 0;
    f2hilo(h0i[32768 + idx], h, l);
    x1h[b*2048 + 1024 + u] = h; x1l[b*2048 + 1024 + u] = l;
}

// ---------------------------------------------------------------------------
// LSTM step via MFMA, split-bf16 3-term (AhBh + AhBl + AlBh ~= fp32).
// M=32 (batch), block owns 16 gate-interleaved rows (= 4 complete units),
// K split 4-way across waves, no LDS staging (direct global fragment loads),
// fused gate nonlinearity + c/h update tail. Grid = 4096/16 = 256 blocks.
// XE: number of leading K columns served from Xe (stride 512); rest from Xr
// (stride 2048).
// ---------------------------------------------------------------------------
template<int K, int XE>
__global__ __launch_bounds__(256) void lstm_mfma_kernel(
    const unsigned short* __restrict__ Xe_h, const unsigned short* __restrict__ Xe_l,
    const unsigned short* __restrict__ Xr_h, const unsigned short* __restrict__ Xr_l,
    const unsigned short* __restrict__ Wh,  const unsigned short* __restrict__ Wl,
    const float* __restrict__ bih, const float* __restrict__ bhh,
    float* __restrict__ c_io,
    unsigned short* __restrict__ d1h, unsigned short* __restrict__ d1l, int d1s, int d1o,
    unsigned short* __restrict__ d2h, unsigned short* __restrict__ d2l, int d2s, int d2o,
    float* __restrict__ hf32)
{
    const int tid = threadIdx.x;
    const int wave = tid >> 6, lane = tid & 63;
    const int quad = lane >> 4, l15 = lane & 15;
    const int n0 = blockIdx.x * 16;
    constexpr int Kq = K >> 2;
    const int kb = wave * Kq;
    const int col = quad * 8;
    f32x4 acc0 = {0.f,0.f,0.f,0.f}, acc1 = {0.f,0.f,0.f,0.f};
    const unsigned short* wrh = Wh + (size_t)(n0 + l15) * K + kb + col;
    const unsigned short* wrl = Wl + (size_t)(n0 + l15) * K + kb + col;
    #pragma unroll 4
    for (int ks = 0; ks < Kq; ks += 32) {
        const int k = kb + ks;
        const unsigned short *ah, *al; int as_;
        if (XE != 0 && k < XE) { ah = Xe_h + k + col; al = Xe_l + k + col; as_ = EMB_; }
        else                   { ah = Xr_h + (k - XE) + col; al = Xr_l + (k - XE) + col; as_ = 2048; }
        bf16x8 a0h = *(const bf16x8*)(ah + l15 * as_);
        bf16x8 a0l = *(const bf16x8*)(al + l15 * as_);
        bf16x8 a1h = *(const bf16x8*)(ah + (16 + l15) * as_);
        bf16x8 a1l = *(const bf16x8*)(al + (16 + l15) * as_);
        bf16x8 bh  = *(const bf16x8*)(wrh + ks);
        bf16x8 bl  = *(const bf16x8*)(wrl + ks);
        acc0 = __builtin_amdgcn_mfma_f32_16x16x32_bf16(a0h, bh, acc0, 0, 0, 0);
        acc1 = __builtin_amdgcn_mfma_f32_16x16x32_bf16(a1h, bh, acc1, 0, 0, 0);
        acc0 = __builtin_amdgcn_mfma_f32_16x16x32_bf16(a0h, bl, acc0, 0, 0, 0);
        acc1 = __builtin_amdgcn_mfma_f32_16x16x32_bf16(a1h, bl, acc1, 0, 0, 0);
        acc0 = __builtin_amdgcn_mfma_f32_16x16x32_bf16(a0l, bh, acc0, 0, 0, 0);
        acc1 = __builtin_amdgcn_mfma_f32_16x16x32_bf16(a1l, bh, acc1, 0, 0, 0);
    }
    __shared__ float Gs[4][32][16];
    __shared__ float Gr[32][16];
    // C/D layout: col = lane&15 (gate row), row = quad*4 + reg (batch) [m89]
    #pragma unroll
    for (int rr = 0; rr < 4; rr++) {
        Gs[wave][quad * 4 + rr][l15]      = acc0[rr];
        Gs[wave][16 + quad * 4 + rr][l15] = acc1[rr];
    }
    __syncthreads();
    #pragma unroll
    for (int it = 0; it < 2; it++) {
        int idx = tid + it * 256;
        int b = idx >> 4, nl = idx & 15;
        float g = Gs[0][b][nl] + Gs[1][b][nl] + Gs[2][b][nl] + Gs[3][b][nl];
        int jn = n0 + nl;
        int j = (jn & 3) * H_ + (jn >> 2);    // original (un-interleaved) row
        Gr[b][nl] = g + bih[j] + bhh[j];
    }
    __syncthreads();
    if (tid < 128) {
        const int b = tid & 31, ul = tid >> 5;
        const int u = (n0 >> 2) + ul;
        const float gi = Gr[b][ul * 4 + 0];
        const float gf = Gr[b][ul * 4 + 1];
        const float gg = Gr[b][ul * 4 + 2];
        const float go = Gr[b][ul * 4 + 3];
        const float cold = c_io[b * H_ + u];
        const float si = 1.f / (1.f + __expf(-gi));
        const float sf = 1.f / (1.f + __expf(-gf));
        const float so = 1.f / (1.f + __expf(-go));
        const float cn = sf * cold + si * tanhf(gg);
        const float hn = so * tanhf(cn);
        c_io[b * H_ + u] = cn;
        unsigned short hh, hl;
        f2hilo(hn, hh, hl);
        d1h[b * d1s + d1o + u] = hh;
        d1l[b * d1s + d1o + u] = hl;
        d2h[b * d2s + d2o + u] = hh;
        d2l[b * d2s + d2o + u] = hl;
        if (hf32) hf32[b * H_ + u] = hn;
    }
}

// ---------------------------------------------------------------------------
// Small GEMM via MFMA split-bf16: out[32, 1024] = X[32,K] @ W[1024,K]^T + bias.
// MODE 0: fp32 out (keybuf). MODE 1: bf16 out (combbf) + hi/lo feed slot.
// Grid = 1024/16 = 64 blocks.
// ---------------------------------------------------------------------------
template<int K, int MODE>
__global__ __launch_bounds__(256) void gemm32_mfma_kernel(
    const unsigned short* __restrict__ Xh, const unsigned short* __restrict__ Xl,
    const unsigned short* __restrict__ Wh, const unsigned short* __restrict__ Wl,
    const float* __restrict__ bias,
    float* __restrict__ outf, unsigned short* __restrict__ outbf,
    unsigned short* __restrict__ dh, unsigned short* __restrict__ dl)
{
    const int tid = threadIdx.x;
    const int wave = tid >> 6, lane = tid & 63;
    const int quad = lane >> 4, l15 = lane & 15;
    const int n0 = blockIdx.x * 16;
    constexpr int Kq = K >> 2;
    const int kb = wave * Kq;
    const int col = quad * 8;
    f32x4 acc0 = {0.f,0.f,0.f,0.f}, acc1 = {0.f,0.f,0.f,0.f};
    const unsigned short* x0h = Xh + (size_t)l15 * K + kb + col;
    const unsigned short* x0l = Xl + (size_t)l15 * K + kb + col;
    const unsigned short* x1h = Xh + (size_t)(16 + l15) * K + kb + col;
    const unsigned short* x1l = Xl + (size_t)(16 + l15) * K + kb + col;
    const unsigned short* wrh = Wh + (size_t)(n0 + l15) * K + kb + col;
    const unsigned short* wrl = Wl + (size_t)(n0 + l15) * K + kb + col;
    #pragma unroll 4
    for (int ks = 0; ks < Kq; ks += 32) {
        bf16x8 a0h = *(const bf16x8*)(x0h + ks);
        bf16x8 a0l = *(const bf16x8*)(x0l + ks);
        bf16x8 a1h = *(const bf16x8*)(x1h + ks);
        bf16x8 a1l = *(const bf16x8*)(x1l + ks);
        bf16x8 bh  = *(const bf16x8*)(wrh + ks);
        bf16x8 bl  = *(const bf16x8*)(wrl + ks);
        acc0 = __builtin_amdgcn_mfma_f32_16x16x32_bf16(a0h, bh, acc0, 0, 0, 0);
        acc1 = __builtin_amdgcn_mfma_f32_16x16x32_bf16(a1h, bh, acc1, 0, 0, 0);
        acc0 = __builtin_amdgcn_mfma_f32_16x16x32_bf16(a0h, bl, acc0, 0, 0, 0);
        acc1 = __builtin_amdgcn_mfma_f32_16x16x32_bf16(a1h, bl, acc1, 0, 0, 0);
        acc0 = __builtin_amdgcn_mfma_f32_16x16x32_bf16(a0l, bh, acc0, 0, 0, 0);
        acc1 = __builtin_amdgcn_mfma_f32_16x16x32_bf16(a1l, bh, acc1, 0, 0, 0);
    }
    __shared__ float Gs[4][32][16];
    #pragma unroll
    for (int rr = 0; rr < 4; rr++) {
        Gs[wave][quad * 4 + rr][l15]      = acc0[rr];
        Gs[wave][16 + quad * 4 + rr][l15] = acc1[rr];
    }
    __syncthreads();
    #pragma unroll
    for (int it = 0; it < 2; it++) {
        int idx = tid + it * 256;
        int b = idx >> 4, nl = idx & 15;
        int n = n0 + nl;
        float v = Gs[0][b][nl] + Gs[1][b][nl] + Gs[2][b][nl] + Gs[3][b][nl] + bias[n];
        if (MODE == 0) {
            outf[b * H_ + n] = v;
        } else {
            outbf[b * H_ + n] = f2bf(v);
            unsigned short hh, hl;
            f2hilo(v, hh, hl);
            dh[b * 2048 + n] = hh;
            dl[b * 2048 + n] = hl;
        }
    }
}

// ---------------------------------------------------------------------------
// Attention for step t (fp32): scores over s<=t, softmax, summary; writes dist
// row and cat = [htop | summary] as bf16 hi/lo. Grid: B blocks.
// ---------------------------------------------------------------------------
__global__ __launch_bounds__(256) void attn_kernel(
    int t, const float* __restrict__ hbuf, const float* __restrict__ keybuf,
    const int* __restrict__ tokens, float* __restrict__ dist_all,
    unsigned short* __restrict__ cat_h, unsigned short* __restrict__ cat_l)
{
    const int bb = blockIdx.x;
    const int tid = threadIdx.x;
    __shared__ float ht[H_];
    __shared__ float sc[T_];
    __shared__ float dsh[T_];
    for (int k = tid; k < H_; k += 256)
        ht[k] = hbuf[((size_t)t * B_ + bb) * H_ + k];
    __syncthreads();
    const int wave = tid >> 6, lane = tid & 63;
    for (int s = wave; s <= t; s += 4) {
        const float* kv = keybuf + ((size_t)s * B_ + bb) * H_;
        float p = 0.f;
        #pragma unroll
        for (int j = 0; j < 16; j++) p += kv[lane + 64 * j] * ht[lane + 64 * j];
        #pragma unroll
        for (int off = 32; off > 0; off >>= 1) p += __shfl_down(p, off, 64);
        if (lane == 0) {
            float pen = (tokens[s * B_ + bb] == 0) ? -99999.0f : 0.0f;
            sc[s] = p + pen;
        }
    }
    __syncthreads();
    if (tid < 64) {
        float v = (tid <= t) ? sc[tid] : -1e30f;
        float m = v;
        #pragma unroll
        for (int off = 32; off > 0; off >>= 1) m = fmaxf(m, __shfl_down(m, off, 64));
        m = __shfl(m, 0, 64);
        float e = (tid <= t) ? __expf(v - m) : 0.f;
        float ss = e;
        #pragma unroll
        for (int off = 32; off > 0; off >>= 1) ss += __shfl_down(ss, off, 64);
        ss = __shfl(ss, 0, 64);
        float d = e / ss;
        dsh[tid] = d;
        if (tid <= t) dist_all[((size_t)t * T_ + tid) * B_ + bb] = d;
    }
    __syncthreads();
    float sm0 = 0.f, sm1 = 0.f, sm2 = 0.f, sm3 = 0.f;
    for (int s = 0; s <= t; s++) {
        const float d = dsh[s];
        const float* hr = hbuf + ((size_t)s * B_ + bb) * H_;
        sm0 += d * hr[tid];
        sm1 += d * hr[tid + 256];
        sm2 += d * hr[tid + 512];
        sm3 += d * hr[tid + 768];
    }
    const int base = bb * 2048;
    unsigned short hh, hl;
    f2hilo(ht[tid],       hh, hl); cat_h[base + tid]        = hh; cat_l[base + tid]        = hl;
    f2hilo(ht[tid + 256], hh, hl); cat_h[base + tid + 256]  = hh; cat_l[base + tid + 256]  = hl;
    f2hilo(ht[tid + 512], hh, hl); cat_h[base + tid + 512]  = hh; cat_l[base + tid + 512]  = hl;
    f2hilo(ht[tid + 768], hh, hl); cat_h[base + tid + 768]  = hh; cat_l[base + tid + 768]  = hl;
    f2hilo(sm0, hh, hl); cat_h[base + 1024 + tid]       = hh; cat_l[base + 1024 + tid]       = hl;
    f2hilo(sm1, hh, hl); cat_h[base + 1024 + tid + 256] = hh; cat_l[base + 1024 + tid + 256] = hl;
    f2hilo(sm2, hh, hl); cat_h[base + 1024 + tid + 512] = hh; cat_l[base + 1024 + tid + 512] = hl;
    f2hilo(sm3, hh, hl); cat_h[base + 1024 + tid + 768] = hh; cat_l[base + 1024 + tid + 768] = hl;
}

// ---------------------------------------------------------------------------
// fp32 -> bf16 cast (n4 float4 groups) — used for Wp only.
// ---------------------------------------------------------------------------
__global__ __launch_bounds__(256) void cast_bf16_kernel(
    const float* __restrict__ src, unsigned short* __restrict__ dst, int n4)
{
    int idx = blockIdx.x * 256 + threadIdx.x;
    int stride = gridDim.x * 256;
    for (int i = idx; i < n4; i += stride) {
        float4 v = ((const float4*)src)[i];
        ushort4 o;
        o.x = f2bf(v.x); o.y = f2bf(v.y); o.z = f2bf(v.z); o.w = f2bf(v.w);
        ((ushort4*)dst)[i] = o;
    }
}

// ---------------------------------------------------------------------------
// Logits GEMM: (2048 x 1024) @ Wp^T (32000 x 1024) + bp, bf16 MFMA 16x16x32.
// ---------------------------------------------------------------------------
__global__ __launch_bounds__(256) void logits_mfma_kernel(
    const __bf16* __restrict__ Abf, const __bf16* __restrict__ Bbf,
    const float* __restrict__ bp, float* __restrict__ out)
{
    __shared__ __align__(16) __bf16 As[128 * 32];
    __shared__ __align__(16) __bf16 Bs[128 * 32];
    const int tid = threadIdx.x;
    const int lane = tid & 63;
    const int wave = tid >> 6;
    const int quad = lane >> 4, l15 = lane & 15;
    const int m0 = blockIdx.y * 128, n0 = blockIdx.x * 128;
    const int wm = wave >> 1, wn = wave & 1;
    const f32x4 vzero = {0.f, 0.f, 0.f, 0.f};
    f32x4 acc[4][4];
    #pragma unroll
    for (int mt = 0; mt < 4; mt++)
        #pragma unroll
        for (int nt = 0; nt < 4; nt++) acc[mt][nt] = vzero;

    for (int k0 = 0; k0 < 1024; k0 += 32) {
        #pragma unroll
        for (int i = 0; i < 2; i++) {
            int idx = i * 256 + tid;
            int row = idx >> 2, co = (idx & 3) * 8;
            ((uint4*)As)[idx] = *(const uint4*)(Abf + (size_t)(m0 + row) * 1024 + k0 + co);
            ((uint4*)Bs)[idx] = *(const uint4*)(Bbf + (size_t)(n0 + row) * 1024 + k0 + co);
        }
        __syncthreads();
        bf16x8 af[4], bfr[4];
        #pragma unroll
        for (int mt = 0; mt < 4; mt++)
            af[mt] = *(const bf16x8*)&As[(wm * 64 + mt * 16 + l15) * 32 + quad * 8];
        #pragma unroll
        for (int nt = 0; nt < 4; nt++)
            bfr[nt] = *(const bf16x8*)&Bs[(wn * 64 + nt * 16 + l15) * 32 + quad * 8];
        #pragma unroll
        for (int mt = 0; mt < 4; mt++)
            #pragma unroll
            for (int nt = 0; nt < 4; nt++)
                acc[mt][nt] = __builtin_amdgcn_mfma_f32_16x16x32_bf16(
                    af[mt], bfr[nt], acc[mt][nt], 0, 0, 0);
        __syncthreads();
    }
    #pragma unroll
    for (int mt = 0; mt < 4; mt++) {
        #pragma unroll
        for (int nt = 0; nt < 4; nt++) {
            int gcol = n0 + wn * 64 + nt * 16 + l15;
            int growb = m0 + wm * 64 + mt * 16 + quad * 4;
            float bpv = bp[gcol];
            #pragma unroll
            for (int rr = 0; rr < 4; rr++)
                out[(size_t)(growb + rr) * V_ + gcol] = acc[mt][nt][rr] + bpv;
        }
    }
}

// ---------------------------------------------------------------------------
// Per-row max / sumexp / copy-weight from fp32 logits. Grid: T*B blocks.
// ---------------------------------------------------------------------------
__global__ __launch_bounds__(256) void rowstats_kernel(
    const float* __restrict__ logits, float* __restrict__ stats)
{
    const int row = blockIdx.x; const int tid = threadIdx.x;
    const float4* p4 = (const float4*)(logits + (size_t)row * V_);
    __shared__ float red[8];
    const int lane = tid & 63, wave = tid >> 6;
    float m = -1e30f;
    for (int i = tid; i < V_ / 4; i += 256) {
        float4 u = p4[i];
        m = fmaxf(m, fmaxf(fmaxf(u.x, u.y), fmaxf(u.z, u.w)));
    }
    #pragma unroll
    for (int off = 32; off > 0; off >>= 1) m = fmaxf(m, __shfl_down(m, off, 64));
    if (lane == 0) red[wave] = m;
    __syncthreads();
    if (tid == 0) {
        float mm = red[0];
        for (int w = 1; w < 4; w++) mm = fmaxf(mm, red[w]);
        red[4] = mm;
    }
    __syncthreads();
    const float M = red[4];
    float s = 0.f;
    for (int i = tid; i < V_ / 4; i += 256) {
        float4 u = p4[i];
        s += __expf(u.x - M) + __expf(u.y - M) + __expf(u.z - M) + __expf(u.w - M);
    }
    #pragma unroll
    for (int off = 32; off > 0; off >>= 1) s += __shfl_down(s, off, 64);
    if (lane == 0) red[wave] = s;
    __syncthreads();
    if (tid == 0) {
        float S = red[0] + red[1] + red[2] + red[3];
        float lc = logits[(size_t)row * V_ + COPY_ID_];
        float cw = __expf(lc - M) / S;
        stats[row * 4 + 0] = M;
        stats[row * 4 + 1] = S;
        stats[row * 4 + 2] = cw;
    }
}

__global__ __launch_bounds__(64) void fixup_compute_kernel(
    const float* __restrict__ logits, const float* __restrict__ stats,
    const int* __restrict__ tokens, const float* __restrict__ dist_all,
    float* __restrict__ fixval)
{
    const int bid = blockIdx.x;          // t*B + b
    const int t = bid >> 5, b = bid & 31;
    const int s = threadIdx.x;
    if (s > t) return;
    const int v = tokens[s * B_ + b];
    float d = 0.f;
    for (int s2 = 0; s2 <= t; s2++)
        if (tokens[s2 * B_ + b] == v)
            d += dist_all[((size_t)t * T_ + s2) * B_ + b];
    const float M = stats[bid * 4], S = stats[bid * 4 + 1], cw = stats[bid * 4 + 2];
    const float l = logits[(size_t)bid * V_ + v];
    const float p = __expf(l - M) / S;
    fixval[((size_t)t * T_ + s) * B_ + b] = __logf(cw * (EPS_ + d) + (1.f - cw) * p);
}

__global__ __launch_bounds__(256) void finalize_kernel(
    float* __restrict__ logits, const float* __restrict__ stats)
{
    const int row = blockIdx.x; const int tid = threadIdx.x;
    float4* p4 = (float4*)(logits + (size_t)row * V_);
    const float M = stats[row * 4], S = stats[row * 4 + 1], cw = stats[row * 4 + 2];
    const float inv = 1.f / S, omc = 1.f - cw, ce = cw * EPS_;
    for (int i = tid; i < V_ / 4; i += 256) {
        float4 u = p4[i];
        u.x = __logf(omc * (__expf(u.x - M) * inv) + ce);
        u.y = __logf(omc * (__expf(u.y - M) * inv) + ce);
        u.z = __logf(omc * (__expf(u.z - M) * inv) + ce);
        u.w = __logf(omc * (__expf(u.w - M) * inv) + ce);
        p4[i] = u;
    }
}

__global__ __launch_bounds__(64) void fixup_apply_kernel(
    float* __restrict__ logits, const int* __restrict__ tokens,
    const float* __restrict__ fixval)
{
    const int bid = blockIdx.x; const int t = bid >> 5, b = bid & 31;
    const int s = threadIdx.x;
    if (s > t) return;
    const int v = tokens[s * B_ + b];
    logits[(size_t)bid * V_ + v] = fixval[((size_t)t * T_ + s) * B_ + b];
}

// ---------------------------------------------------------------------------
extern "C" void kernel_launch(void* const* d_in, const int* in_sizes, int n_in,
                              void* d_out, int out_size, void* d_ws, size_t ws_size,
                              hipStream_t stream)
{
    const int*   tok  = (const int*)d_in[0];
    const float* h0i  = (const float*)d_in[1];
    const float* c0i  = (const float*)d_in[2];
    const float* E    = (const float*)d_in[3];
    const float* Wih0 = (const float*)d_in[4];
    const float* Whh0 = (const float*)d_in[5];
    const float* bih0 = (const float*)d_in[6];
    const float* bhh0 = (const float*)d_in[7];
    const float* Wih1 = (const float*)d_in[8];
    const float* Whh1 = (const float*)d_in[9];
    const float* bih1 = (const float*)d_in[10];
    const float* bhh1 = (const float*)d_in[11];
    const float* Wk   = (const float*)d_in[12];
    const float* bk   = (const float*)d_in[13];
    const float* Wc   = (const float*)d_in[14];
    const float* bc   = (const float*)d_in[15];
    const float* Wp   = (const float*)d_in[16];
    const float* bp   = (const float*)d_in[17];
    float* out = (float*)d_out;

    // ---- workspace (fp32 side) ----
    float* ws = (float*)d_ws;
    size_t off = 0;
    float* hbuf   = ws + off; off += (size_t)T_ * B_ * H_;     // fp32 htop, attn input
    float* keybuf = ws + off; off += (size_t)T_ * B_ * H_;
    float* dist   = ws + off; off += (size_t)T_ * T_ * B_;
    float* fixv   = ws + off; off += (size_t)T_ * T_ * B_;
    float* c0b    = ws + off; off += B_ * H_;
    float* c1b    = ws + off; off += B_ * H_;
    float* stats  = ws + off; off += (size_t)T_ * B_ * 4;
    unsigned short* combbf = (unsigned short*)(ws + off); off += (size_t)T_ * B_ * H_ / 2;
    unsigned short* Wpbf   = (unsigned short*)(ws + off); off += (size_t)V_ * H_ / 2;

    // ---- scratch carved from d_out (262 MB; only the epilogue writes logits,
    //      all of this is dead by then). ~102 MB total. ----
    unsigned short* os = (unsigned short*)d_out;
    size_t so = 0;
    unsigned short* W0h = os + so; so += (size_t)4096 * 2560;
    unsigned short* W0l = os + so; so += (size_t)4096 * 2560;
    unsigned short* W1h = os + so; so += (size_t)4096 * 2048;
    unsigned short* W1l = os + so; so += (size_t)4096 * 2048;
    unsigned short* Wkh = os + so; so += (size_t)1024 * 1024;
    unsigned short* Wkl = os + so; so += (size_t)1024 * 1024;
    unsigned short* Wch = os + so; so += (size_t)1024 * 2048;
    unsigned short* Wcl = os + so; so += (size_t)1024 * 2048;
    unsigned short* Xeh = os + so; so += (size_t)T_ * B_ * EMB_;
    unsigned short* Xel = os + so; so += (size_t)T_ * B_ * EMB_;
    unsigned short* xr0h = os + so; so += (size_t)2 * B_ * 2048;  // [2][32][feed|h0prev]
    unsigned short* xr0l = os + so; so += (size_t)2 * B_ * 2048;
    unsigned short* xr1h = os + so; so += (size_t)2 * B_ * 2048;  // [2][32][h0cur|h1prev]
    unsigned short* xr1l = os + so; so += (size_t)2 * B_ * 2048;
    unsigned short* hbh  = os + so; so += (size_t)T_ * B_ * H_;   // htop hi (keyv input)
    unsigned short* hbl  = os + so; so += (size_t)T_ * B_ * H_;
    unsigned short* cath = os + so; so += (size_t)B_ * 2048;
    unsigned short* catl = os + so; so += (size_t)B_ * 2048;

    // ---- one-time prep ----
    hipMemcpyAsync(c0b, c0i,           B_ * H_ * 4, hipMemcpyDeviceToDevice, stream);
    hipMemcpyAsync(c1b, c0i + B_ * H_, B_ * H_ * 4, hipMemcpyDeviceToDevice, stream);
    pack_gates_kernel<<<10240, 256, 0, stream>>>(Wih0, 1536, Whh0, 2560, W0h, W0l);
    pack_gates_kernel<<<8192,  256, 0, stream>>>(Wih1, 1024, Whh1, 2048, W1h, W1l);
    pack_plain_kernel<<<1024,  256, 0, stream>>>(Wk, Wkh, Wkl, 1024 * 1024 / 4);
    pack_plain_kernel<<<2048,  256, 0, stream>>>(Wc, Wch, Wcl, 1024 * 2048 / 4);
    embed_hilo_kernel<<<1024,  256, 0, stream>>>(E, tok, Xeh, Xel);
    init_states_kernel<<<128,  256, 0, stream>>>(h0i, xr0h, xr0l, xr1h, xr1l);
    cast_bf16_kernel<<<2048,   256, 0, stream>>>(Wp, Wpbf, V_ * H_ / 4);

    // ---- recurrent loop ----
    for (int t = 0; t < T_; t++) {
        const size_t cur = (size_t)(t & 1) * B_ * 2048;
        const size_t nxt = (size_t)((t + 1) & 1) * B_ * 2048;
        const size_t to1 = (size_t)t * B_ * H_;
        // layer 0: X = [Xe(t) | feed | h0prev]; h -> xr0.next.hprev + xr1.cur.h0
        lstm_mfma_kernel<2560, 512><<<256, 256, 0, stream>>>(
            Xeh + (size_t)t * B_ * EMB_, Xel + (size_t)t * B_ * EMB_,
            xr0h + cur, xr0l + cur, W0h, W0l, bih0, bhh0, c0b,
            xr0h + nxt, xr0l + nxt, 2048, 1024,
            xr1h + cur, xr1l + cur, 2048, 0,
            nullptr);
        // layer 1: X = [h0cur | h1prev]; h -> xr1.next.hprev + hbuf hi/lo + fp32
        lstm_mfma_kernel<2048, 0><<<256, 256, 0, stream>>>(
            xr1h + cur, xr1l + cur,
            xr1h + cur, xr1l + cur, W1h, W1l, bih1, bhh1, c1b,
            xr1h + nxt, xr1l + nxt, 2048, 1024,
            hbh + to1, hbl + to1, 1024, 0,
            hbuf + to1);
        // keyv(t) = htop @ Wk^T + bk  (fp32 out)
        gemm32_mfma_kernel<1024, 0><<<64, 256, 0, stream>>>(
            hbh + to1, hbl + to1, Wkh, Wkl, bk,
            keybuf + to1, nullptr, nullptr, nullptr);
        attn_kernel<<<B_, 256, 0, stream>>>(t, hbuf, keybuf, tok, dist, cath, catl);
        // comb(t) = cat @ Wc^T + bc  -> combbf (logits input) + next feed slot
        gemm32_mfma_kernel<2048, 1><<<64, 256, 0, stream>>>(
            cath, catl, Wch, Wcl, bc,
            nullptr, combbf + to1, xr0h + nxt, xr0l + nxt);
    }

    // ---- epilogue (overwrites the d_out scratch with real logits) ----
    dim3 g1(V_ / 128, (T_ * B_) / 128);
    logits_mfma_kernel<<<g1, 256, 0, stream>>>(
        (const __bf16*)combbf, (const __bf16*)Wpbf, bp, out);
    rowstats_kernel<<<T_ * B_, 256, 0, stream>>>(out, stats);
    fixup_compute_kernel<<<T_ * B_, T_, 0, stream>>>(out, stats, tok, dist, fixv);
    finalize_kernel<<<T_ * B_, 256, 0, stream>>>(out, stats);
    fixup_apply_kernel<<<T_ * B_, T_, 0, stream>>>(out, tok, fixv);
}